// Round 1
// baseline (185.945 us; speedup 1.0000x reference)
//
#include <hip/hip_runtime.h>

// Problem constants (from reference)
#define VOCAB 50257
#define SEQ   2048
#define EMB   512
#define BATCH 8
#define NTOK  (BATCH * SEQ)   // 16384

typedef float floatx4 __attribute__((ext_vector_type(4)));

// ---------------------------------------------------------------------------
// Workspace layout (ints):
//   cnt       @ 0        (50432)  token histogram over vocab
//   endcur    @ 50432    (50432)  exclusive-scan start cursors -> end after fill
//   bsum      @ 100864   (256)    per-256-chunk partial sums
//   positions @ 101120   (16384)  CSR payload: output-row ids bucketed by vocab
//   total ~470 KB
// ---------------------------------------------------------------------------
#define CNT_OFF   0
#define CUR_OFF   50432
#define BSUM_OFF  100864
#define POS_OFF   101120
#define WS_INTS   (POS_OFF + NTOK)
#define NBLK      197            // ceil(VOCAB/256)

__global__ __launch_bounds__(256)
void zero_k(int* __restrict__ cnt) {
    const int i = blockIdx.x * 256 + threadIdx.x;
    if (i < VOCAB) cnt[i] = 0;
}

__global__ __launch_bounds__(256)
void hist_k(const int* __restrict__ tokens, int* __restrict__ cnt) {
    const int i = blockIdx.x * 256 + threadIdx.x;   // grid = NTOK/256
    atomicAdd(&cnt[tokens[i]], 1);
}

// Per-256-chunk sums of cnt.
__global__ __launch_bounds__(256)
void scan_partial_k(const int* __restrict__ cnt, int* __restrict__ bsum) {
    const int tid = threadIdx.x;
    const int v   = blockIdx.x * 256 + tid;
    int c = (v < VOCAB) ? cnt[v] : 0;
#pragma unroll
    for (int d = 32; d > 0; d >>= 1) c += __shfl_down(c, d);
    __shared__ int rb[4];
    if ((tid & 63) == 0) rb[tid >> 6] = c;
    __syncthreads();
    if (tid == 0) bsum[blockIdx.x] = rb[0] + rb[1] + rb[2] + rb[3];
}

// endcur[v] = exclusive prefix sum of cnt (start cursor for bucket v).
__global__ __launch_bounds__(256)
void scan_offsets_k(const int* __restrict__ cnt, const int* __restrict__ bsum,
                    int* __restrict__ endcur) {
    __shared__ int sb[256];
    __shared__ int rb[4];
    __shared__ int wsum[4];
    const int b   = blockIdx.x;
    const int tid = threadIdx.x;
    if (tid < NBLK) sb[tid] = bsum[tid];
    __syncthreads();
    // base = sum of bsum[0..b)
    int base = 0;
    for (int k = tid; k < b; k += 256) base += sb[k];
#pragma unroll
    for (int d = 32; d > 0; d >>= 1) base += __shfl_down(base, d);
    if ((tid & 63) == 0) rb[tid >> 6] = base;
    __syncthreads();
    const int base_total = rb[0] + rb[1] + rb[2] + rb[3];
    // block-local inclusive scan of cnt
    const int v = b * 256 + tid;
    const int c = (v < VOCAB) ? cnt[v] : 0;
    int x = c;
#pragma unroll
    for (int d = 1; d < 64; d <<= 1) {
        const int y = __shfl_up(x, d);
        if ((tid & 63) >= d) x += y;
    }
    if ((tid & 63) == 63) wsum[tid >> 6] = x;
    __syncthreads();
    int wbase = 0;
    for (int w = 0; w < (tid >> 6); ++w) wbase += wsum[w];
    if (v < VOCAB) endcur[v] = base_total + wbase + x - c;   // exclusive
}

// Bucket every output row id by its token. After this, endcur[v] = start+count.
__global__ __launch_bounds__(256)
void fill_k(const int* __restrict__ tokens, int* __restrict__ endcur,
            int* __restrict__ positions) {
    const int i = blockIdx.x * 256 + threadIdx.x;   // grid = NTOK/256
    const int t = tokens[i];
    const int p = atomicAdd(&endcur[t], 1);
    positions[p] = i;
}

// Fused transpose + scatter + positional add.
// Reads W_emb fully coalesced (256 B/wave-inst rows), LDS-transposes a 64x64
// tile, then writes each used column DIRECTLY to all its output rows as
// aligned 256 B segments (nontemporal). No intermediate table, no gather pass.
__global__ __launch_bounds__(256)
void scatter_k(const float* __restrict__ in,        // (EMB, VOCAB)
               const int* __restrict__ cnt,
               const int* __restrict__ endcur,      // = start + count
               const int* __restrict__ positions,
               const float* __restrict__ Wpos,      // (SEQ, EMB)
               float* __restrict__ out) {           // (NTOK, EMB)
    __shared__ float tile[64][65];
    __shared__ int used_v[64];
    __shared__ int used_st[64];
    __shared__ int used_n[64];
    __shared__ int nused_s;
    const int v0 = blockIdx.x * 64;
    const int e0 = blockIdx.y * 64;
    const int tx = threadIdx.x;   // 0..63 (lane)
    const int ty = threadIdx.y;   // 0..3  (wave)
    const int v  = v0 + tx;
    const bool vok = (v < VOCAB);

    // Stage 64x64 tile; each wave-inst reads 256 B contiguous of one e-row.
    if (vok) {
        const float* rp = in + (size_t)(e0 + ty) * VOCAB + v;
#pragma unroll
        for (int j = 0; j < 16; ++j)
            tile[4 * j + ty][tx] = rp[(size_t)(4 * j) * VOCAB];
    }
    // Wave 0 compacts used columns (count>0) with their CSR ranges.
    if (ty == 0) {
        const int n = vok ? cnt[v] : 0;
        const unsigned long long m = __ballot(n > 0);
        const int pos = __popcll(m & ((1ull << tx) - 1ull));
        if (n > 0) {
            used_v[pos]  = tx;
            used_n[pos]  = n;
            used_st[pos] = endcur[v] - n;   // start of bucket
        }
        if (tx == 0) nused_s = (int)__popcll(m);
    }
    __syncthreads();
    const int nused = nused_s;
    // Each used column -> one 256 B write per occurrence, fused +Wpos.
    for (int u = ty; u < nused; u += 4) {
        const int vl = used_v[u];
        const int n  = used_n[u];
        const int st = used_st[u];
        const float val = tile[tx][vl];         // (tx+vl)%32: 2-way, free
        for (int k = 0; k < n; ++k) {
            const int p = positions[st + k];    // wave-uniform -> s_load
            const int s = p & (SEQ - 1);
            const float r = val + Wpos[(size_t)s * EMB + e0 + tx];
            __builtin_nontemporal_store(r, &out[(size_t)p * EMB + e0 + tx]);
        }
    }
}

// Fallback: direct strided gather (correct anywhere, slow).
__global__ __launch_bounds__(256)
void gather_direct_k(const int* __restrict__ tokens,
                     const float* __restrict__ W_emb,
                     const floatx4* __restrict__ Wpos,
                     floatx4* __restrict__ out) {
    const int idx = blockIdx.x * blockDim.x + threadIdx.x;
    const int e4  = idx & (EMB / 4 - 1);
    const int ts  = idx >> 7;
    const int s   = ts & (SEQ - 1);
    const int t   = tokens[ts];
    const size_t base = (size_t)(4 * e4) * VOCAB + (size_t)t;
    floatx4 r;
    r.x = W_emb[base];
    r.y = W_emb[base + (size_t)VOCAB];
    r.z = W_emb[base + (size_t)(2 * VOCAB)];
    r.w = W_emb[base + (size_t)(3 * VOCAB)];
    __builtin_nontemporal_store(r + Wpos[(size_t)s * (EMB / 4) + e4], &out[idx]);
}

extern "C" void kernel_launch(void* const* d_in, const int* in_sizes, int n_in,
                              void* d_out, int out_size, void* d_ws, size_t ws_size,
                              hipStream_t stream) {
    const int*   tokens = (const int*)d_in[0];
    const float* W_emb  = (const float*)d_in[1];   // (EMB, VOCAB)
    const float* W_pos  = (const float*)d_in[2];   // (SEQ, EMB)
    float*       out    = (float*)d_out;           // (BATCH, SEQ, EMB)

    const size_t need = (size_t)WS_INTS * sizeof(int);   // ~470 KB
    if (ws_size >= need) {
        int* cnt       = (int*)d_ws + CNT_OFF;
        int* endcur    = (int*)d_ws + CUR_OFF;
        int* bsum      = (int*)d_ws + BSUM_OFF;
        int* positions = (int*)d_ws + POS_OFF;

        zero_k<<<NBLK, 256, 0, stream>>>(cnt);
        hist_k<<<NTOK / 256, 256, 0, stream>>>(tokens, cnt);
        scan_partial_k<<<NBLK, 256, 0, stream>>>(cnt, bsum);
        scan_offsets_k<<<NBLK, 256, 0, stream>>>(cnt, bsum, endcur);
        fill_k<<<NTOK / 256, 256, 0, stream>>>(tokens, endcur, positions);
        scatter_k<<<dim3((VOCAB + 63) / 64, EMB / 64), dim3(64, 4), 0, stream>>>(
            W_emb, cnt, endcur, positions, W_pos, out);
    } else {
        const int n_out4  = BATCH * SEQ * (EMB / 4);
        const int gblocks = n_out4 / 256;
        gather_direct_k<<<gblocks, 256, 0, stream>>>(tokens, W_emb,
                                                     (const floatx4*)W_pos,
                                                     (floatx4*)out);
    }
}